// Round 3
// baseline (635.179 us; speedup 1.0000x reference)
//
#include <hip/hip_runtime.h>
#include <math.h>

// Problem constants
#define GG 256            // graphs
#define NN 128            // nodes per graph
#define NTOT (GG*NN)      // 32768
#define EPG 2048          // edges per graph (N*DEG)
#define EDGES (GG*EPG)    // 524288
#define HID 256
#define DH 64             // head dim (HID/4)

typedef __attribute__((ext_vector_type(8))) short short8;
typedef __attribute__((ext_vector_type(4))) float f32x4;

__device__ __forceinline__ ushort f2bf(float f){
  union { float f; unsigned u; } x; x.f = f;
  unsigned r = x.u + 0x7fffu + ((x.u >> 16) & 1u);   // RNE
  return (ushort)(r >> 16);
}
__device__ __forceinline__ float bf2f(ushort h){
  union { unsigned u; float f; } x; x.u = ((unsigned)h) << 16;
  return x.f;
}

// ---------------------------------------------------------------------------
// Dense per-graph adjacency build.
// AdjG[g][i][j] = #edges(src=j,dst=i) + (i==j)   stored bf16 (exact, small ints)
// dinv[i] = rsqrt(in_deg + 1)
// ---------------------------------------------------------------------------
__global__ __launch_bounds__(256) void adj_build(
    const int* __restrict__ src, const int* __restrict__ dst,
    ushort* __restrict__ adjg, float* __restrict__ dinv)
{
  __shared__ unsigned hist[NN*NN];        // [src][dst], 64 KB
  int g = blockIdx.x, t = threadIdx.x;
  int base = g*EPG, nb = g*NN;
  for (int i=t; i<NN*NN; i+=256) hist[i]=0u;
  __syncthreads();
  {
    int4 a = *(const int4*)(src + base + t*8);
    int4 b = *(const int4*)(src + base + t*8 + 4);
    int4 c = *(const int4*)(dst + base + t*8);
    int4 d = *(const int4*)(dst + base + t*8 + 4);
    atomicAdd(&hist[(a.x-nb)*NN + (c.x-nb)], 1u);
    atomicAdd(&hist[(a.y-nb)*NN + (c.y-nb)], 1u);
    atomicAdd(&hist[(a.z-nb)*NN + (c.z-nb)], 1u);
    atomicAdd(&hist[(a.w-nb)*NN + (c.w-nb)], 1u);
    atomicAdd(&hist[(b.x-nb)*NN + (d.x-nb)], 1u);
    atomicAdd(&hist[(b.y-nb)*NN + (d.y-nb)], 1u);
    atomicAdd(&hist[(b.z-nb)*NN + (d.z-nb)], 1u);
    atomicAdd(&hist[(b.w-nb)*NN + (d.w-nb)], 1u);
  }
  __syncthreads();
  if (t < NN){
    unsigned dg = 0;
    for (int k=0; k<NN; k++) dg += hist[k*NN + t];   // column sum: conflict-free
    dinv[nb + t] = rsqrtf((float)dg + 1.0f);
  }
  __syncthreads();
  ushort* out = adjg + (size_t)g*NN*NN;
  for (int idx=t; idx<NN*NN; idx+=256){
    int i = idx >> 7, j = idx & 127;                 // row i = dst, col j = src
    unsigned cnt = hist[j*NN + i];
    float v = (float)cnt + ((i==j) ? 1.0f : 0.0f);
    out[idx] = f2bf(v);                              // exact for small ints
  }
}

// ---------------------------------------------------------------------------
// Legacy LDS aggregation matmul, used ONLY for GIN layer 0 (CI=128, raw x
// input which has no producing mm to pre-transpose it).
// ---------------------------------------------------------------------------
template<int CI, int MODE>
__global__ __launch_bounds__(256) void agg_mfma(
    const ushort* __restrict__ adjg,
    const float* __restrict__ X0, const float* __restrict__ X1,
    const float* __restrict__ aux,
    const float* __restrict__ b0, const float* __restrict__ b1,
    float* __restrict__ out0, float* __restrict__ out1)
{
  __shared__ ushort Al[128][72];
  __shared__ ushort Bh[128][76];
  __shared__ ushort Bl2[128][76];
  const int g = blockIdx.x;
  int bn, sel = 0;
  if (MODE==2){ sel = blockIdx.y >> 1; bn = (blockIdx.y & 1)*128; }
  else bn = blockIdx.y*128;
  const float* X    = (MODE==2 && sel) ? X1 : X0;
  const float* bias = (MODE==2) ? (sel ? b1 : b0) : nullptr;
  float* out        = (MODE==2 && sel) ? out1 : out0;
  const int t = threadIdx.x;
  const int w = t>>6, l = t&63;
  const int wr = w>>1, wc = w&1;
  const int c16 = l&15, g16 = l>>4;
  f32x4 acc[4][4];
  #pragma unroll
  for (int i=0;i<4;i++)
    #pragma unroll
    for (int j=0;j<4;j++) acc[i][j] = (f32x4){0.f,0.f,0.f,0.f};
  const ushort* ag = adjg + (size_t)g*NN*NN;

  for (int kk0=0; kk0<128; kk0+=64){
    #pragma unroll
    for (int it=0; it<4; it++){
      int idx = it*256 + t;
      int r = idx>>3, c8 = (idx&7)*8;
      *(short8*)&Al[r][c8] = *(const short8*)(ag + r*NN + kk0 + c8);
    }
    #pragma unroll
    for (int it=0; it<8; it++){
      int linear = it*256 + t;
      int jl = linear>>5, c4l = (linear&31)*4;
      if (CI==128 && c4l >= CI) continue;
      int node = g*NN + kk0 + jl;
      float4 v = *(const float4*)(X + (size_t)node*CI + bn + c4l);
      if (MODE==1){
        float4 s  = *(const float4*)(aux + bn + c4l);
        float4 hh = *(const float4*)(aux + 256 + bn + c4l);
        v.x=fmaxf(v.x*s.x+hh.x,0.f); v.y=fmaxf(v.y*s.y+hh.y,0.f);
        v.z=fmaxf(v.z*s.z+hh.z,0.f); v.w=fmaxf(v.w*s.w+hh.w,0.f);
      } else if (MODE==2){
        float dv = aux[node];
        v.x*=dv; v.y*=dv; v.z*=dv; v.w*=dv;
      }
      float vv[4] = {v.x, v.y, v.z, v.w};
      #pragma unroll
      for (int q=0;q<4;q++){
        ushort hb = f2bf(vv[q]);
        ushort lb = f2bf(vv[q] - bf2f(hb));
        Bh[c4l+q][jl]  = hb;
        Bl2[c4l+q][jl] = lb;
      }
    }
    __syncthreads();
    #pragma unroll
    for (int kk=0; kk<64; kk+=32){
      short8 af[4], bh[4], bl[4];
      #pragma unroll
      for (int i=0;i<4;i++) af[i] = *(short8*)&Al[wr*64+i*16+c16][kk+g16*8];
      #pragma unroll
      for (int j=0;j<4;j++) bh[j] = *(short8*)&Bh[wc*64+j*16+c16][kk+g16*8];
      #pragma unroll
      for (int j=0;j<4;j++) bl[j] = *(short8*)&Bl2[wc*64+j*16+c16][kk+g16*8];
      #pragma unroll
      for (int i=0;i<4;i++)
        #pragma unroll
        for (int j=0;j<4;j++){
          acc[i][j] = __builtin_amdgcn_mfma_f32_16x16x32_bf16(af[i], bh[j], acc[i][j], 0,0,0);
          acc[i][j] = __builtin_amdgcn_mfma_f32_16x16x32_bf16(af[i], bl[j], acc[i][j], 0,0,0);
        }
    }
    __syncthreads();
  }
  #pragma unroll
  for (int i=0;i<4;i++){
    #pragma unroll
    for (int j=0;j<4;j++){
      #pragma unroll
      for (int r=0;r<4;r++){
        int row = wr*64 + i*16 + g16*4 + r;
        int col = bn + wc*64 + j*16 + c16;
        float v = acc[i][j][r];
        if (MODE==2) v = v*aux[(size_t)g*NN + row] + bias[col];
        out[((size_t)g*NN + row)*CI + col] = v;
      }
    }
  }
}

// ---------------------------------------------------------------------------
// LDS-free dense aggregation: out[128][256] = Adj[128x128] @ X (per graph).
// B operand read DIRECTLY from pre-transposed bf16 hi/lo planes
// (plane[ch][node], hi at 0, lo at +plo) written by the producing mm.
// MODE 1: GIN-1, f = relu((hi+lo)*scl+shf) per channel, re-split at load.
// MODE 2: GCN, planes already hold xw*dinv_j; epilogue v = v*dinv_i + bias.
// ---------------------------------------------------------------------------
template<int MODE>
__global__ __launch_bounds__(256) void agg_gemm(
    const ushort* __restrict__ adjg,
    const ushort* __restrict__ P0, const ushort* __restrict__ P1, size_t plo,
    const float* __restrict__ aux,       // stats (MODE1) or dinv (MODE2)
    const float* __restrict__ b0, const float* __restrict__ b1,
    float* __restrict__ out0, float* __restrict__ out1)
{
  const int g = blockIdx.x;
  int bn, sel = 0;
  if (MODE==2){ sel = blockIdx.y >> 1; bn = (blockIdx.y & 1)*128; }
  else bn = blockIdx.y*128;
  const ushort* Ph = (MODE==2 && sel) ? P1 : P0;
  const ushort* Pl = Ph + plo;
  const float* bias = (MODE==2) ? (sel ? b1 : b0) : nullptr;
  float* out = (MODE==2 && sel) ? out1 : out0;
  const int t = threadIdx.x;
  const int w = t>>6, l = t&63;
  const int wr = w>>1, wc = w&1;
  const int c16 = l&15, g16 = l>>4;
  const size_t nbase = (size_t)g*NN;
  f32x4 acc[4][4];
  #pragma unroll
  for (int i=0;i<4;i++)
    #pragma unroll
    for (int j=0;j<4;j++) acc[i][j] = (f32x4){0.f,0.f,0.f,0.f};
  const ushort* ag = adjg + (size_t)g*NN*NN;

  float sclj[4], shfj[4];
  if (MODE==1){
    #pragma unroll
    for (int j=0;j<4;j++){
      int col = bn + wc*64 + j*16 + c16;
      sclj[j] = aux[col]; shfj[j] = aux[256+col];
    }
  }

  for (int kk=0; kk<128; kk+=32){
    short8 af[4];
    #pragma unroll
    for (int i=0;i<4;i++)
      af[i] = *(const short8*)(ag + (wr*64+i*16+c16)*NN + kk + g16*8);
    short8 bh[4], bl[4];
    #pragma unroll
    for (int j=0;j<4;j++){
      int col = bn + wc*64 + j*16 + c16;
      size_t off = (size_t)col*NTOT + nbase + kk + g16*8;
      short8 h8 = *(const short8*)(Ph + off);
      short8 l8 = *(const short8*)(Pl + off);
      if (MODE==1){
        #pragma unroll
        for (int e=0;e<8;e++){
          float v = bf2f((ushort)h8[e]) + bf2f((ushort)l8[e]);
          v = fmaxf(v*sclj[j] + shfj[j], 0.f);
          ushort hb = f2bf(v);
          h8[e] = (short)hb;
          l8[e] = (short)f2bf(v - bf2f(hb));
        }
      }
      bh[j] = h8; bl[j] = l8;
    }
    #pragma unroll
    for (int i=0;i<4;i++)
      #pragma unroll
      for (int j=0;j<4;j++){
        acc[i][j] = __builtin_amdgcn_mfma_f32_16x16x32_bf16(af[i], bh[j], acc[i][j], 0,0,0);
        acc[i][j] = __builtin_amdgcn_mfma_f32_16x16x32_bf16(af[i], bl[j], acc[i][j], 0,0,0);
      }
  }
  #pragma unroll
  for (int i=0;i<4;i++){
    float4 di4 = make_float4(1.f,1.f,1.f,1.f);
    if (MODE==2) di4 = *(const float4*)(aux + nbase + wr*64 + i*16 + g16*4);
    #pragma unroll
    for (int j=0;j<4;j++){
      int col = bn + wc*64 + j*16 + c16;
      #pragma unroll
      for (int r=0;r<4;r++){
        int row = wr*64 + i*16 + g16*4 + r;
        float v = acc[i][j][r];
        if (MODE==2) v = v*(&di4.x)[r] + bias[col];
        out[(nbase + row)*HID + col] = v;
      }
    }
  }
}

// ---------------------------------------------------------------------------
// Weight prep: fp32 W[K,N] -> bf16 Wt[N,K], 64x64 LDS tile transpose.
// ---------------------------------------------------------------------------
struct PrepW { const float* w; int K; int N; };
struct PrepArgs { PrepW e[16]; };

__global__ __launch_bounds__(256) void prep_weights(PrepArgs pa, ushort* __restrict__ wtb)
{
  __shared__ ushort T[64][72];
  int wi = blockIdx.x;
  const float* W = pa.e[wi].w;
  int K = pa.e[wi].K, N = pa.e[wi].N;
  int tk_n = K>>6, tn_n = N>>6;
  int tile = blockIdx.y;
  if (tile >= tk_n*tn_n) return;
  int tk = tile % tk_n, tn = tile / tk_n;
  int t = threadIdx.x;
  int kr = t>>2, n0 = (t&3)*16;
  #pragma unroll
  for (int j=0;j<4;j++){
    float4 v = *(const float4*)(W + (size_t)(tk*64+kr)*N + tn*64 + n0 + j*4);
    T[n0+j*4+0][kr] = f2bf(v.x);
    T[n0+j*4+1][kr] = f2bf(v.y);
    T[n0+j*4+2][kr] = f2bf(v.z);
    T[n0+j*4+3][kr] = f2bf(v.w);
  }
  __syncthreads();
  ushort* out = wtb + (size_t)wi*65536;
  int nr = t>>2, k0 = (t&3)*16;
  *(short8*)(out + (size_t)(tn*64+nr)*K + tk*64 + k0)     = *(short8*)&T[nr][k0];
  *(short8*)(out + (size_t)(tn*64+nr)*K + tk*64 + k0 + 8) = *(short8*)&T[nr][k0+8];
}

// ---------------------------------------------------------------------------
// BatchNorm stats finalize (partials produced by mm_bf16 epilogue)
// ---------------------------------------------------------------------------
__global__ __launch_bounds__(256) void bn_final(const float* __restrict__ part,
    const float* __restrict__ gamma, const float* __restrict__ beta, float* __restrict__ stats)
{
  int c = threadIdx.x;                           // grid 1, block 256
  float s=0.f, s2=0.f;
  for (int b=0;b<256;b++){ s += part[b*256+c]; s2 += part[65536 + b*256+c]; }
  const float invn = 1.0f/(float)NTOT;
  float mean = s*invn;
  float var  = s2*invn - mean*mean;
  float scl  = gamma[c]*rsqrtf(var + 1e-5f);
  stats[c]     = scl;
  stats[256+c] = beta[c] - mean*scl;
}

// ---------------------------------------------------------------------------
// bf16 MFMA matmul: out[M,N] = A'[M,K] @ Wt[N,K](bf16) + bias.
// ATR=1: A' = relu(A*scale+shift).   EPI==1: out = skip + relu(out).
// BNF=1: fuse per-column batch-stat partials (sum, sumsq) into `part`.
// TW=1 : write transposed bf16 hi/lo planes twp[col*NTOT + row] (hi),
//        +nplanes*NTOT (lo), via LDS transpose for fully-coalesced 128 B/thread
//        stores; optional per-row scale rscale[row] folded before the split.
// ---------------------------------------------------------------------------
template<int EPI, int ATR, int BNF, int TW>
__global__ __launch_bounds__(256) void mm_bf16(
    const float* __restrict__ A, const ushort* __restrict__ Wt,
    const float* __restrict__ bias, const float* __restrict__ skip,
    const float* __restrict__ bnst,
    float* __restrict__ out, ushort* __restrict__ twp,
    const float* __restrict__ rscale, float* __restrict__ part,
    int nplanes, int M, int K, int N)
{
  __shared__ ushort SM[18432];       // Al[128][72] | Bl[128][72]; reused as Tt[128][136]
  __shared__ float bns[4][4][16];
  __shared__ float bns2[4][4][16];
  ushort (*Al)[72] = (ushort (*)[72])SM;
  ushort (*Bl)[72] = (ushort (*)[72])(SM + 9216);
  const int t = threadIdx.x;
  const int bm = blockIdx.x*128, bn = blockIdx.y*128;
  const int w = t>>6, l = t&63;
  const int wr = w>>1, wc = w&1;
  const int c16 = l&15, g16 = l>>4;
  const int sr = t>>1, sc = (t&1)*32;
  f32x4 acc[4][4];
  #pragma unroll
  for (int i=0;i<4;i++)
    #pragma unroll
    for (int j=0;j<4;j++) acc[i][j] = (f32x4){0.f,0.f,0.f,0.f};

  for (int k0=0; k0<K; k0+=64){
    const float* ap = A + (size_t)(bm+sr)*K + k0 + sc;
    #pragma unroll
    for (int j=0;j<4;j++){
      float4 v0 = *(const float4*)(ap + j*8);
      float4 v1 = *(const float4*)(ap + j*8 + 4);
      if (ATR){
        int cb = k0 + sc + j*8;
        float4 s0 = *(const float4*)(bnst + cb);
        float4 s1 = *(const float4*)(bnst + cb + 4);
        float4 h0 = *(const float4*)(bnst + 256 + cb);
        float4 h1 = *(const float4*)(bnst + 256 + cb + 4);
        v0.x=fmaxf(v0.x*s0.x+h0.x,0.f); v0.y=fmaxf(v0.y*s0.y+h0.y,0.f);
        v0.z=fmaxf(v0.z*s0.z+h0.z,0.f); v0.w=fmaxf(v0.w*s0.w+h0.w,0.f);
        v1.x=fmaxf(v1.x*s1.x+h1.x,0.f); v1.y=fmaxf(v1.y*s1.y+h1.y,0.f);
        v1.z=fmaxf(v1.z*s1.z+h1.z,0.f); v1.w=fmaxf(v1.w*s1.w+h1.w,0.f);
      }
      short8 p;
      p[0]=(short)f2bf(v0.x); p[1]=(short)f2bf(v0.y); p[2]=(short)f2bf(v0.z); p[3]=(short)f2bf(v0.w);
      p[4]=(short)f2bf(v1.x); p[5]=(short)f2bf(v1.y); p[6]=(short)f2bf(v1.z); p[7]=(short)f2bf(v1.w);
      *(short8*)&Al[sr][sc+j*8] = p;
    }
    const ushort* bp = Wt + (size_t)(bn+sr)*K + k0 + sc;
    #pragma unroll
    for (int j=0;j<4;j++)
      *(short8*)&Bl[sr][sc+j*8] = *(const short8*)(bp + j*8);
    __syncthreads();
    #pragma unroll
    for (int kk=0; kk<64; kk+=32){
      short8 af[4], bf[4];
      #pragma unroll
      for (int i=0;i<4;i++) af[i] = *(short8*)&Al[wr*64+i*16+c16][kk+g16*8];
      #pragma unroll
      for (int i=0;i<4;i++) bf[i] = *(short8*)&Bl[wc*64+i*16+c16][kk+g16*8];
      #pragma unroll
      for (int i=0;i<4;i++)
        #pragma unroll
        for (int j=0;j<4;j++)
          acc[i][j] = __builtin_amdgcn_mfma_f32_16x16x32_bf16(af[i], bf[j], acc[i][j], 0,0,0);
    }
    __syncthreads();
  }

  float sj[4]  = {0.f,0.f,0.f,0.f};
  float s2j[4] = {0.f,0.f,0.f,0.f};

  if (TW){
    // ---- coalesced transposed hi/lo plane writes via LDS transpose ----
    ushort (*Tt)[136] = (ushort (*)[136])SM;   // 128*136*2 = 34816 B, fits in SM
    // pass 0: hi plane (+ batch stats)
    #pragma unroll
    for (int i=0;i<4;i++){
      const int r0l = wr*64 + i*16 + g16*4;
      float4 rs = make_float4(1.f,1.f,1.f,1.f);
      if (rscale) rs = *(const float4*)(rscale + bm + r0l);
      #pragma unroll
      for (int j=0;j<4;j++){
        const int coll = wc*64 + j*16 + c16;
        const float bv = bias ? bias[bn+coll] : 0.f;
        ushort4 h4;
        #pragma unroll
        for (int r=0;r<4;r++){
          float v = acc[i][j][r] + bv;
          if (BNF){ sj[j]+=v; s2j[j]+=v*v; }
          float sv = v * (&rs.x)[r];
          (&h4.x)[r] = f2bf(sv);
        }
        *(ushort4*)&Tt[coll][r0l] = h4;
      }
    }
    if (BNF){
      #pragma unroll
      for (int j=0;j<4;j++){
        float s = sj[j], s2 = s2j[j];
        s  += __shfl_xor(s, 16);  s  += __shfl_xor(s, 32);
        s2 += __shfl_xor(s2,16);  s2 += __shfl_xor(s2,32);
        if (g16==0){ bns[w][j][c16] = s; bns2[w][j][c16] = s2; }
      }
    }
    __syncthreads();
    if (BNF && t < 128){
      int wcL = t>>6, jL = (t>>4)&3, cL = t&15;
      float s  = bns [wcL][jL][cL] + bns [2+wcL][jL][cL];
      float s2 = bns2[wcL][jL][cL] + bns2[2+wcL][jL][cL];
      part[(bm>>7)*256 + bn + t]         = s;
      part[65536 + (bm>>7)*256 + bn + t] = s2;
    }
    const int coll2 = t>>1, seg = t&1;
    {
      ushort* dsth = twp + (size_t)(bn+coll2)*NTOT + bm + seg*64;
      #pragma unroll
      for (int m=0;m<8;m++)
        *(short8*)(dsth + m*8) = *(short8*)&Tt[coll2][seg*64 + m*8];
    }
    __syncthreads();
    // pass 1: lo plane (residual recomputed from acc)
    #pragma unroll
    for (int i=0;i<4;i++){
      const int r0l = wr*64 + i*16 + g16*4;
      float4 rs = make_float4(1.f,1.f,1.f,1.f);
      if (rscale) rs = *(const float4*)(rscale + bm + r0l);
      #pragma unroll
      for (int j=0;j<4;j++){
        const int coll = wc*64 + j*16 + c16;
        const float bv = bias ? bias[bn+coll] : 0.f;
        ushort4 l4;
        #pragma unroll
        for (int r=0;r<4;r++){
          float v = acc[i][j][r] + bv;
          float sv = v * (&rs.x)[r];
          ushort hb = f2bf(sv);
          (&l4.x)[r] = f2bf(sv - bf2f(hb));
        }
        *(ushort4*)&Tt[coll][r0l] = l4;
      }
    }
    __syncthreads();
    {
      ushort* dstl = twp + (size_t)nplanes*NTOT + (size_t)(bn+coll2)*NTOT + bm + seg*64;
      #pragma unroll
      for (int m=0;m<8;m++)
        *(short8*)(dstl + m*8) = *(short8*)&Tt[coll2][seg*64 + m*8];
    }
  } else {
    #pragma unroll
    for (int i=0;i<4;i++){
      #pragma unroll
      for (int j=0;j<4;j++){
        int col = bn + wc*64 + j*16 + c16;
        float bv = bias ? bias[col] : 0.f;
        #pragma unroll
        for (int r=0;r<4;r++){
          int row = bm + wr*64 + i*16 + g16*4 + r;
          float v = acc[i][j][r] + bv;
          if (BNF){ sj[j]+=v; s2j[j]+=v*v; }
          if (EPI==1) v = skip[(size_t)row*N+col] + fmaxf(v,0.f);
          out[(size_t)row*N+col] = v;
        }
      }
    }
    if (BNF){
      #pragma unroll
      for (int j=0;j<4;j++){
        float s = sj[j], s2 = s2j[j];
        s  += __shfl_xor(s, 16);  s  += __shfl_xor(s, 32);
        s2 += __shfl_xor(s2,16);  s2 += __shfl_xor(s2,32);
        if (g16==0){ bns[w][j][c16] = s; bns2[w][j][c16] = s2; }
      }
      __syncthreads();
      if (t < 128){
        int wcL = t>>6, jL = (t>>4)&3, cL = t&15;
        float s  = bns [wcL][jL][cL] + bns [2+wcL][jL][cL];
        float s2 = bns2[wcL][jL][cL] + bns2[2+wcL][jL][cL];
        part[(bm>>7)*256 + bn + t]         = s;
        part[65536 + (bm>>7)*256 + bn + t] = s2;
      }
    }
  }
}

// ---------------------------------------------------------------------------
// fp32 tiled matmul (tiny M: qp1 M=75, qp3 M=1)
// ---------------------------------------------------------------------------
template<int EPI>
__global__ __launch_bounds__(256) void mm_kernel(
    const float* __restrict__ A, const float* __restrict__ W,
    const float* __restrict__ bias, const float* __restrict__ skip,
    float* __restrict__ out, int M, int K, int N)
{
  __shared__ float As[16][68];   // [k][m]
  __shared__ float Ws[16][68];   // [k][n]
  const int t  = threadIdx.x;
  const int bm = blockIdx.x*64, bn = blockIdx.y*64;
  const int tx = t & 15, ty = t >> 4;
  const int lrow = t >> 2;
  const int lkc  = (t & 3) * 4;
  const int wkr  = t >> 4;
  const int wnc  = (t & 15) * 4;
  float acc[4][4] = {{0.f}};
  for (int k0 = 0; k0 < K; k0 += 16) {
    float4 av = make_float4(0.f,0.f,0.f,0.f);
    if (bm + lrow < M) av = *(const float4*)(A + (size_t)(bm+lrow)*K + k0 + lkc);
    float4 wv = *(const float4*)(W + (size_t)(k0+wkr)*N + bn + wnc);
    As[lkc+0][lrow]=av.x; As[lkc+1][lrow]=av.y; As[lkc+2][lrow]=av.z; As[lkc+3][lrow]=av.w;
    *(float4*)&Ws[wkr][wnc] = wv;
    __syncthreads();
    #pragma unroll
    for (int kk=0; kk<16; kk++){
      float4 a4 = *(float4*)&As[kk][ty*4];
      float4 b4 = *(float4*)&Ws[kk][tx*4];
      acc[0][0]+=a4.x*b4.x; acc[0][1]+=a4.x*b4.y; acc[0][2]+=a4.x*b4.z; acc[0][3]+=a4.x*b4.w;
      acc[1][0]+=a4.y*b4.x; acc[1][1]+=a4.y*b4.y; acc[1][2]+=a4.y*b4.z; acc[1][3]+=a4.y*b4.w;
      acc[2][0]+=a4.z*b4.x; acc[2][1]+=a4.z*b4.y; acc[2][2]+=a4.z*b4.z; acc[2][3]+=a4.z*b4.w;
      acc[3][0]+=a4.w*b4.x; acc[3][1]+=a4.w*b4.y; acc[3][2]+=a4.w*b4.z; acc[3][3]+=a4.w*b4.w;
    }
    __syncthreads();
  }
  #pragma unroll
  for (int i=0;i<4;i++){
    int r = bm + ty*4 + i;
    if (r >= M) continue;
    #pragma unroll
    for (int j=0;j<4;j++){
      int c = bn + tx*4 + j;
      float v = acc[i][j] + (bias ? bias[c] : 0.f);
      if (EPI==1) v = skip[(size_t)r*N + c] + fmaxf(v, 0.f);
      out[(size_t)r*N + c] = v;
    }
  }
}

// ---------------------------------------------------------------------------
// MFMA attention (validated). Block=(graph,head), 4 waves.
// ---------------------------------------------------------------------------
__global__ __launch_bounds__(256) void attn_mfma(
    const float* __restrict__ Qp, const float* __restrict__ Kd, const float* __restrict__ Vd,
    float* __restrict__ O, int qlen, int klen, int qgstride)
{
  __shared__ ushort Kbf[128*72];
  __shared__ ushort Vt[64*136];
  __shared__ ushort Pws[4][16*136];
  int g = blockIdx.x, h = blockIdx.y;
  int hd0 = h*DH;
  int t = threadIdx.x, w = t>>6, l = t&63;

  for (int idx=t; idx<128*16; idx+=256){
    int k = idx>>4, d4 = (idx&15)*4;
    float4 kv = make_float4(0.f,0.f,0.f,0.f), vv = kv;
    if (k < klen){
      kv = *(const float4*)(Kd + ((size_t)g*klen + k)*HID + hd0 + d4);
      vv = *(const float4*)(Vd + ((size_t)g*klen + k)*HID + hd0 + d4);
    }
    ushort4 kb = make_ushort4(f2bf(kv.x), f2bf(kv.y), f2bf(kv.z), f2bf(kv.w));
    *(ushort4*)&Kbf[k*72 + d4] = kb;
    Vt[(d4+0)*136 + k] = f2bf(vv.x);
    Vt[(d4+1)*136 + k] = f2bf(vv.y);
    Vt[(d4+2)*136 + k] = f2bf(vv.z);
    Vt[(d4+3)*136 + k] = f2bf(vv.w);
  }
  __syncthreads();

  const int c16 = l & 15, g16 = l >> 4;
  const float scl = 1.0f/16.0f;
  int qtiles = (qlen + 15) >> 4;
  for (int qt = w; qt < qtiles; qt += 4){
    int qbase = qt*16;
    int qrow = qbase + c16; if (qrow > qlen-1) qrow = qlen-1;
    const float* qr = Qp + (size_t)g*qgstride + (size_t)qrow*HID + hd0 + g16*8;
    short8 qa[2];
    #pragma unroll
    for (int dh=0; dh<2; dh++){
      float4 x0 = *(const float4*)(qr + dh*32);
      float4 x1 = *(const float4*)(qr + dh*32 + 4);
      short8 f;
      f[0]=(short)f2bf(x0.x); f[1]=(short)f2bf(x0.y); f[2]=(short)f2bf(x0.z); f[3]=(short)f2bf(x0.w);
      f[4]=(short)f2bf(x1.x); f[5]=(short)f2bf(x1.y); f[6]=(short)f2bf(x1.z); f[7]=(short)f2bf(x1.w);
      qa[dh]=f;
    }
    float p[8][4];
    #pragma unroll
    for (int kt=0; kt<8; kt++){
      f32x4 a = {0.f,0.f,0.f,0.f};
      short8 b0 = *(short8*)&Kbf[(kt*16+c16)*72 + g16*8];
      short8 b1 = *(short8*)&Kbf[(kt*16+c16)*72 + 32 + g16*8];
      a = __builtin_amdgcn_mfma_f32_16x16x32_bf16(qa[0], b0, a, 0,0,0);
      a = __builtin_amdgcn_mfma_f32_16x16x32_bf16(qa[1], b1, a, 0,0,0);
      int k = kt*16 + c16;
      #pragma unroll
      for (int r=0; r<4; r++) p[kt][r] = (k < klen) ? a[r]*scl : -1e30f;
    }
    float m[4], sum[4];
    #pragma unroll
    for (int r=0; r<4; r++){
      float mm = p[0][r];
      #pragma unroll
      for (int kt=1; kt<8; kt++) mm = fmaxf(mm, p[kt][r]);
      for (int o=1; o<16; o<<=1) mm = fmaxf(mm, __shfl_xor(mm, o));
      m[r] = mm;
    }
    #pragma unroll
    for (int r=0; r<4; r++){
      float s = 0.f;
      #pragma unroll
      for (int kt=0; kt<8; kt++){ p[kt][r] = __expf(p[kt][r]-m[r]); s += p[kt][r]; }
      for (int o=1; o<16; o<<=1) s += __shfl_xor(s, o);
      sum[r] = 1.0f/s;
    }
    #pragma unroll
    for (int kt=0; kt<8; kt++)
      #pragma unroll
      for (int r=0; r<4; r++)
        Pws[w][(g16*4+r)*136 + kt*16 + c16] = f2bf(p[kt][r]*sum[r]);
    #pragma unroll
    for (int dt=0; dt<4; dt++){
      f32x4 o4 = {0.f,0.f,0.f,0.f};
      #pragma unroll
      for (int ks=0; ks<4; ks++){
        short8 pa = *(short8*)&Pws[w][c16*136 + ks*32 + g16*8];
        short8 vb = *(short8*)&Vt[(dt*16+c16)*136 + ks*32 + g16*8];
        o4 = __builtin_amdgcn_mfma_f32_16x16x32_bf16(pa, vb, o4, 0,0,0);
      }
      #pragma unroll
      for (int r=0; r<4; r++){
        int q2 = qbase + g16*4 + r;
        if (q2 < qlen){
          int col = hd0 + dt*16 + c16;
          O[((size_t)g*qlen + q2)*HID + col] =
              Qp[(size_t)g*qgstride + (size_t)q2*HID + col] + o4[r];
        }
      }
    }
  }
}

// ---------------------------------------------------------------------------
extern "C" void kernel_launch(void* const* d_in, const int* in_sizes, int n_in,
                              void* d_out, int out_size, void* d_ws, size_t ws_size,
                              hipStream_t stream)
{
  (void)in_sizes; (void)n_in; (void)out_size; (void)ws_size;
  const float* x      = (const float*)d_in[0];
  const int*   ei     = (const int*)d_in[1];
  const float* g0_W1=(const float*)d_in[3],  *g0_b1=(const float*)d_in[4],  *g0_ga1=(const float*)d_in[5],  *g0_be1=(const float*)d_in[6];
  const float* g0_W2=(const float*)d_in[7],  *g0_b2=(const float*)d_in[8],  *g0_ga2=(const float*)d_in[9],  *g0_be2=(const float*)d_in[10];
  const float* g1_W1=(const float*)d_in[11], *g1_b1=(const float*)d_in[12], *g1_ga1=(const float*)d_in[13], *g1_be1=(const float*)d_in[14];
  const float* g1_W2=(const float*)d_in[15], *g1_b2=(const float*)d_in[16], *g1_ga2=(const float*)d_in[17], *g1_be2=(const float*)d_in[18];
  const float* lin1_W=(const float*)d_in[19], *lin1_b=(const float*)d_in[20];
  const float* S1=(const float*)d_in[21];
  const float* p1_Wq=(const float*)d_in[22], *p1_Wk=(const float*)d_in[23], *p1_Wv=(const float*)d_in[24], *p1_Wo=(const float*)d_in[25];
  const float* p1_bq=(const float*)d_in[26], *p1_bk=(const float*)d_in[27], *p1_bv=(const float*)d_in[28], *p1_bo=(const float*)d_in[29];
  const float* s2_Wq=(const float*)d_in[30], *s2_Wk=(const float*)d_in[31], *s2_Wv=(const float*)d_in[32], *s2_Wo=(const float*)d_in[33];
  const float* s2_bq=(const float*)d_in[34], *s2_bk=(const float*)d_in[35], *s2_bv=(const float*)d_in[36], *s2_bo=(const float*)d_in[37];
  const float* p3_Wq=(const float*)d_in[38], *p3_Wk=(const float*)d_in[39], *p3_Wv=(const float*)d_in[40], *p3_Wo=(const float*)d_in[41];
  const float* p3_bq=(const float*)d_in[42], *p3_bk=(const float*)d_in[43], *p3_bv=(const float*)d_in[44], *p3_bo=(const float*)d_in[45];
  const float* S3=(const float*)d_in[46];
  const float* lin2_W=(const float*)d_in[47], *lin2_b=(const float*)d_in[48];

  const int* src = ei;
  const int* dst = ei + EDGES;

  // workspace layout (~146 MB)
  float* F = (float*)d_ws;
  const size_t SZ = (size_t)NTOT*HID;              // 8388608 floats
  float* R0=F, *R1=F+SZ, *R2=F+2*SZ, *R3=F+3*SZ;   // R1,R2 adjacent (KV planes)
  float* part  = F + 4*SZ;           // 131072
  float* stats = part + 131072;      // 512
  float* dinv  = stats + 512;        // 32768
  float* qp1   = dinv + 32768;       // 19200
  float* qp3   = qp1 + 19200;        // 256
  float* o3    = qp3 + 256;          // 65536
  float* xf    = o3 + 65536;         // 65536
  ushort* adjg = (ushort*)(xf + 65536);            // GG*16384 bf16 = 8.39 MB
  ushort* wtb  = adjg + (size_t)GG*NN*NN;          // 16*65536 bf16

  const dim3 B256(256);
  const dim3 mmBig(256,2), mmMid(150,2);
  #define WT(i) (wtb + (size_t)(i)*65536)

  // --- weight prep (16 weights -> bf16 transposed) ---
  PrepArgs pa;
  pa.e[0]  = {g0_W1, 128, 256};
  pa.e[1]  = {g0_W2, 256, 256};
  pa.e[2]  = {g1_W1, 256, 256};
  pa.e[3]  = {g1_W2, 256, 256};
  pa.e[4]  = {lin1_W,256, 256};
  pa.e[5]  = {p1_Wk, 256, 256};
  pa.e[6]  = {p1_Wv, 256, 256};
  pa.e[7]  = {p1_Wo, 256, 256};
  pa.e[8]  = {s2_Wk, 256, 256};
  pa.e[9]  = {s2_Wv, 256, 256};
  pa.e[10] = {s2_Wq, 256, 256};
  pa.e[11] = {s2_Wo, 256, 256};
  pa.e[12] = {p3_Wk, 256, 256};
  pa.e[13] = {p3_Wv, 256, 256};
  pa.e[14] = {p3_Wo, 256, 256};
  pa.e[15] = {lin2_W,256, 128};
  prep_weights<<<dim3(16,16),B256,0,stream>>>(pa, wtb);

  // --- graph structure: dense per-graph adjacency ---
  adj_build<<<GG,B256,0,stream>>>(src,dst,adjg,dinv);

  // --- GIN layer 0 ---
  agg_mfma<128,0><<<dim3(GG,1),B256,0,stream>>>(adjg, x, nullptr, nullptr, nullptr, nullptr, R0, nullptr);
  mm_bf16<0,0,1,0><<<mmBig,B256,0,stream>>>(R0, WT(0), g0_b1, nullptr, nullptr, R1, nullptr, nullptr, part, 0, NTOT,128,HID);
  bn_final<<<1,B256,0,stream>>>(part, g0_ga1, g0_be1, stats);
  // h2 = relu(bn1(h1)) @ W2 + b2 : write bf16 hi/lo planes (for agg1) + bn partials
  mm_bf16<0,1,1,1><<<mmBig,B256,0,stream>>>(R1, WT(1), g0_b2, nullptr, stats, nullptr, (ushort*)R2, nullptr, part, 256, NTOT,256,HID);
  bn_final<<<1,B256,0,stream>>>(part, g0_ga2, g0_be2, stats);

  // --- GIN layer 1 (bn2+outer-relu of layer0 fused at plane load) ---
  agg_gemm<1><<<dim3(GG,2),B256,0,stream>>>(adjg, (ushort*)R2, nullptr, (size_t)256*NTOT, stats, nullptr, nullptr, R0, nullptr);
  mm_bf16<0,0,1,0><<<mmBig,B256,0,stream>>>(R0, WT(2), g1_b1, nullptr, nullptr, R1, nullptr, nullptr, part, 0, NTOT,256,HID);
  bn_final<<<1,B256,0,stream>>>(part, g1_ga1, g1_be1, stats);
  mm_bf16<0,1,1,0><<<mmBig,B256,0,stream>>>(R1, WT(3), g1_b2, nullptr, stats, R2, nullptr, nullptr, part, 0, NTOT,256,HID);
  bn_final<<<1,B256,0,stream>>>(part, g1_ga2, g1_be2, stats);

  // --- lin1 (bn2+outer-relu of layer1 fused into A-stage) ---
  mm_bf16<0,1,0,0><<<mmBig,B256,0,stream>>>(R2, WT(4), lin1_b, nullptr, stats, R0, nullptr, nullptr, nullptr, 0, NTOT,256,HID); // xl -> R0

  // --- GMPool_G (p1): K,V planes in ONE fused N=512 dispatch (WT5|WT6 adjacent,
  //     R1|R2 adjacent: K hi @0, V hi @256N, K lo @512N, V lo @768N), dinv folded ---
  mm_bf16<0,0,0,1><<<dim3(256,4),B256,0,stream>>>(R0, WT(5), nullptr, nullptr, nullptr, nullptr, (ushort*)R1, dinv, nullptr, 512, NTOT,256,512);
  agg_gemm<2><<<dim3(GG,4),B256,0,stream>>>(adjg, (ushort*)R1, (ushort*)R1 + (size_t)256*NTOT, (size_t)512*NTOT, dinv, p1_bk, p1_bv, R0, R3); // Kd->R0, Vd->R3
  mm_kernel<0><<<dim3(2,4),B256,0,stream>>>(S1, p1_Wq, p1_bq, nullptr, qp1, 75,256,HID);
  attn_mfma<<<dim3(GG,4),B256,0,stream>>>(qp1, R0, R3, R1, 75,128, 0);     // O1 -> R1
  mm_bf16<1,0,0,0><<<mmMid,B256,0,stream>>>(R1, WT(7), p1_bo, R1, nullptr, R2, nullptr, nullptr, nullptr, 0, 19200,256,HID); // Xp -> R2

  // --- SelfAtt (s2) ---
  mm_bf16<0,0,0,0><<<mmMid,B256,0,stream>>>(R2, WT(8),  s2_bk, nullptr, nullptr, R0, nullptr, nullptr, nullptr, 0, 19200,256,HID);
  mm_bf16<0,0,0,0><<<mmMid,B256,0,stream>>>(R2, WT(9),  s2_bv, nullptr, nullptr, R3, nullptr, nullptr, nullptr, 0, 19200,256,HID);
  mm_bf16<0,0,0,0><<<mmMid,B256,0,stream>>>(R2, WT(10), s2_bq, nullptr, nullptr, R1, nullptr, nullptr, nullptr, 0, 19200,256,HID);
  attn_mfma<<<dim3(GG,4),B256,0,stream>>>(R1, R0, R3, R2, 75,75, 75*HID);  // O2 -> R2
  mm_bf16<1,0,0,0><<<mmMid,B256,0,stream>>>(R2, WT(11), s2_bo, R2, nullptr, R0, nullptr, nullptr, nullptr, 0, 19200,256,HID); // Xp2 -> R0

  // --- GMPool_I (p3) ---
  mm_bf16<0,0,0,0><<<mmMid,B256,0,stream>>>(R0, WT(12), p3_bk, nullptr, nullptr, R1, nullptr, nullptr, nullptr, 0, 19200,256,HID);
  mm_bf16<0,0,0,0><<<mmMid,B256,0,stream>>>(R0, WT(13), p3_bv, nullptr, nullptr, R2, nullptr, nullptr, nullptr, 0, 19200,256,HID);
  mm_kernel<0><<<dim3(1,4),B256,0,stream>>>(S3, p3_Wq, p3_bq, nullptr, qp3, 1,256,HID);
  attn_mfma<<<dim3(GG,4),B256,0,stream>>>(qp3, R1, R2, o3, 1,75, 0);       // O3 -> [G,256]
  mm_bf16<1,0,0,0><<<dim3(2,2),B256,0,stream>>>(o3, WT(14), p3_bo, o3, nullptr, xf, nullptr, nullptr, nullptr, 0, 256,256,HID);

  // --- lin2 ---
  mm_bf16<0,0,0,0><<<dim3(2,1),B256,0,stream>>>(xf, WT(15), lin2_b, nullptr, nullptr, (float*)d_out, nullptr, nullptr, nullptr, 0, 256,256,128);
}

// Round 4
// 530.794 us; speedup vs baseline: 1.1967x; 1.1967x over previous
//
#include <hip/hip_runtime.h>
#include <math.h>

// Problem constants
#define GG 256            // graphs
#define NN 128            // nodes per graph
#define NTOT (GG*NN)      // 32768
#define EPG 2048          // edges per graph (N*DEG)
#define EDGES (GG*EPG)    // 524288
#define HID 256
#define DH 64             // head dim (HID/4)

typedef __attribute__((ext_vector_type(8))) short short8;
typedef __attribute__((ext_vector_type(4))) float f32x4;

__device__ __forceinline__ ushort f2bf(float f){
  union { float f; unsigned u; } x; x.f = f;
  unsigned r = x.u + 0x7fffu + ((x.u >> 16) & 1u);   // RNE
  return (ushort)(r >> 16);
}
__device__ __forceinline__ float bf2f(ushort h){
  union { unsigned u; float f; } x; x.u = ((unsigned)h) << 16;
  return x.f;
}
// Node permutation within each 64-row block: plane position p holds row R(p).
// R swaps the i (16-stride) and g16 (4-stride) digits of the MFMA C layout so
// a lane's 16 accumulator values are CONTIGUOUS in plane space (64B/line/col).
__device__ __forceinline__ int permR(int p){
  return ((p>>2)&3)*16 + ((p>>4)&3)*4 + (p&3) + (p&64);
}

// ---------------------------------------------------------------------------
// Dense per-graph adjacency build (COLUMNS PERMUTED by permR).
// AdjG[g][i][kp] = #edges(src=permR(kp),dst=i) + (i==permR(kp))  (bf16 exact)
// dinv[i] = rsqrt(in_deg + 1)
// ---------------------------------------------------------------------------
__global__ __launch_bounds__(256) void adj_build(
    const int* __restrict__ src, const int* __restrict__ dst,
    ushort* __restrict__ adjg, float* __restrict__ dinv)
{
  __shared__ unsigned hist[NN*NN];        // [src][dst], 64 KB
  int g = blockIdx.x, t = threadIdx.x;
  int base = g*EPG, nb = g*NN;
  for (int i=t; i<NN*NN; i+=256) hist[i]=0u;
  __syncthreads();
  {
    int4 a = *(const int4*)(src + base + t*8);
    int4 b = *(const int4*)(src + base + t*8 + 4);
    int4 c = *(const int4*)(dst + base + t*8);
    int4 d = *(const int4*)(dst + base + t*8 + 4);
    atomicAdd(&hist[(a.x-nb)*NN + (c.x-nb)], 1u);
    atomicAdd(&hist[(a.y-nb)*NN + (c.y-nb)], 1u);
    atomicAdd(&hist[(a.z-nb)*NN + (c.z-nb)], 1u);
    atomicAdd(&hist[(a.w-nb)*NN + (c.w-nb)], 1u);
    atomicAdd(&hist[(b.x-nb)*NN + (d.x-nb)], 1u);
    atomicAdd(&hist[(b.y-nb)*NN + (d.y-nb)], 1u);
    atomicAdd(&hist[(b.z-nb)*NN + (d.z-nb)], 1u);
    atomicAdd(&hist[(b.w-nb)*NN + (d.w-nb)], 1u);
  }
  __syncthreads();
  if (t < NN){
    unsigned dg = 0;
    for (int k=0; k<NN; k++) dg += hist[k*NN + t];   // column sum: conflict-free
    dinv[nb + t] = rsqrtf((float)dg + 1.0f);
  }
  __syncthreads();
  ushort* out = adjg + (size_t)g*NN*NN;
  for (int idx=t; idx<NN*NN; idx+=256){
    int i = idx >> 7, kp = idx & 127;                // row i = dst, col pos kp
    int j = permR(kp);                               // original src node
    unsigned cnt = hist[j*NN + i];
    float v = (float)cnt + ((i==j) ? 1.0f : 0.0f);
    out[idx] = f2bf(v);                              // exact for small ints
  }
}

// ---------------------------------------------------------------------------
// Legacy LDS aggregation matmul, used ONLY for GIN layer 0 (CI=128, raw fp32 x
// input). B staged in permuted column order to match the permuted adjacency.
// ---------------------------------------------------------------------------
template<int CI, int MODE>
__global__ __launch_bounds__(256) void agg_mfma(
    const ushort* __restrict__ adjg,
    const float* __restrict__ X0,
    float* __restrict__ out0)
{
  __shared__ ushort Al[128][72];
  __shared__ ushort Bh[128][76];
  __shared__ ushort Bl2[128][76];
  const int g = blockIdx.x;
  const int bn = blockIdx.y*128;
  const float* X = X0;
  float* out = out0;
  const int t = threadIdx.x;
  const int w = t>>6, l = t&63;
  const int wr = w>>1, wc = w&1;
  const int c16 = l&15, g16 = l>>4;
  f32x4 acc[4][4];
  #pragma unroll
  for (int i=0;i<4;i++)
    #pragma unroll
    for (int j=0;j<4;j++) acc[i][j] = (f32x4){0.f,0.f,0.f,0.f};
  const ushort* ag = adjg + (size_t)g*NN*NN;

  for (int kk0=0; kk0<128; kk0+=64){
    #pragma unroll
    for (int it=0; it<4; it++){
      int idx = it*256 + t;
      int r = idx>>3, c8 = (idx&7)*8;
      *(short8*)&Al[r][c8] = *(const short8*)(ag + r*NN + kk0 + c8);
    }
    #pragma unroll
    for (int it=0; it<8; it++){
      int linear = it*256 + t;
      int jl = linear>>5, c4l = (linear&31)*4;
      int node = g*NN + permR(kk0 + jl);     // permuted source node
      float4 v = *(const float4*)(X + (size_t)node*CI + bn + c4l);
      float vv[4] = {v.x, v.y, v.z, v.w};
      #pragma unroll
      for (int q=0;q<4;q++){
        ushort hb = f2bf(vv[q]);
        ushort lb = f2bf(vv[q] - bf2f(hb));
        Bh[c4l+q][jl]  = hb;
        Bl2[c4l+q][jl] = lb;
      }
    }
    __syncthreads();
    #pragma unroll
    for (int kk=0; kk<64; kk+=32){
      short8 af[4], bh[4], bl[4];
      #pragma unroll
      for (int i=0;i<4;i++) af[i] = *(short8*)&Al[wr*64+i*16+c16][kk+g16*8];
      #pragma unroll
      for (int j=0;j<4;j++) bh[j] = *(short8*)&Bh[wc*64+j*16+c16][kk+g16*8];
      #pragma unroll
      for (int j=0;j<4;j++) bl[j] = *(short8*)&Bl2[wc*64+j*16+c16][kk+g16*8];
      #pragma unroll
      for (int i=0;i<4;i++)
        #pragma unroll
        for (int j=0;j<4;j++){
          acc[i][j] = __builtin_amdgcn_mfma_f32_16x16x32_bf16(af[i], bh[j], acc[i][j], 0,0,0);
          acc[i][j] = __builtin_amdgcn_mfma_f32_16x16x32_bf16(af[i], bl[j], acc[i][j], 0,0,0);
        }
    }
    __syncthreads();
  }
  #pragma unroll
  for (int i=0;i<4;i++){
    #pragma unroll
    for (int j=0;j<4;j++){
      #pragma unroll
      for (int r=0;r<4;r++){
        int row = wr*64 + i*16 + g16*4 + r;
        int col = bn + wc*64 + j*16 + c16;
        out[((size_t)g*NN + row)*CI + col] = acc[i][j][r];
      }
    }
  }
}

// ---------------------------------------------------------------------------
// LDS-free dense aggregation: out[128][256] = Adj[128x128] @ X (per graph).
// B read from permuted interleaved bf16 planes: per col (2*NTOT ushorts),
// 16-node chunks alternate hi|lo:  q_hi = 2*(k' & ~15) + (k'&15), lo at +16.
// MODE 1: GIN-1, f = relu((hi+lo)*scl+shf) per channel, re-split at load.
// MODE 2: GCN, planes hold xw*dinv_j; epilogue v = v*dinv_i + bias.
// ---------------------------------------------------------------------------
template<int MODE>
__global__ __launch_bounds__(256) void agg_gemm(
    const ushort* __restrict__ adjg,
    const ushort* __restrict__ P0, const ushort* __restrict__ P1,
    const float* __restrict__ aux,       // stats (MODE1) or dinv (MODE2)
    const float* __restrict__ b0, const float* __restrict__ b1,
    float* __restrict__ out0, float* __restrict__ out1)
{
  const int g = blockIdx.x;
  int bn, sel = 0;
  if (MODE==2){ sel = blockIdx.y >> 1; bn = (blockIdx.y & 1)*128; }
  else bn = blockIdx.y*128;
  const ushort* Ph = (MODE==2 && sel) ? P1 : P0;
  const float* bias = (MODE==2) ? (sel ? b1 : b0) : nullptr;
  float* out = (MODE==2 && sel) ? out1 : out0;
  const int t = threadIdx.x;
  const int w = t>>6, l = t&63;
  const int wr = w>>1, wc = w&1;
  const int c16 = l&15, g16 = l>>4;
  const size_t nbase = (size_t)g*NN;
  f32x4 acc[4][4];
  #pragma unroll
  for (int i=0;i<4;i++)
    #pragma unroll
    for (int j=0;j<4;j++) acc[i][j] = (f32x4){0.f,0.f,0.f,0.f};
  const ushort* ag = adjg + (size_t)g*NN*NN;

  float sclj[4], shfj[4];
  if (MODE==1){
    #pragma unroll
    for (int j=0;j<4;j++){
      int col = bn + wc*64 + j*16 + c16;
      sclj[j] = aux[col]; shfj[j] = aux[256+col];
    }
  }

  for (int kk=0; kk<128; kk+=32){
    short8 af[4];
    #pragma unroll
    for (int i=0;i<4;i++)
      af[i] = *(const short8*)(ag + (wr*64+i*16+c16)*NN + kk + g16*8);
    short8 bh[4], bl[4];
    size_t khi = 2*(nbase + kk + g16*8) - (size_t)((g16&1)*8);
    #pragma unroll
    for (int j=0;j<4;j++){
      int col = bn + wc*64 + j*16 + c16;
      const ushort* cb = Ph + (size_t)col*(size_t)(2*NTOT);
      short8 h8 = *(const short8*)(cb + khi);
      short8 l8 = *(const short8*)(cb + khi + 16);
      if (MODE==1){
        #pragma unroll
        for (int e=0;e<8;e++){
          float v = bf2f((ushort)h8[e]) + bf2f((ushort)l8[e]);
          v = fmaxf(v*sclj[j] + shfj[j], 0.f);
          ushort hb = f2bf(v);
          h8[e] = (short)hb;
          l8[e] = (short)f2bf(v - bf2f(hb));
        }
      }
      bh[j] = h8; bl[j] = l8;
    }
    #pragma unroll
    for (int i=0;i<4;i++)
      #pragma unroll
      for (int j=0;j<4;j++){
        acc[i][j] = __builtin_amdgcn_mfma_f32_16x16x32_bf16(af[i], bh[j], acc[i][j], 0,0,0);
        acc[i][j] = __builtin_amdgcn_mfma_f32_16x16x32_bf16(af[i], bl[j], acc[i][j], 0,0,0);
      }
  }
  #pragma unroll
  for (int i=0;i<4;i++){
    float4 di4 = make_float4(1.f,1.f,1.f,1.f);
    if (MODE==2) di4 = *(const float4*)(aux + nbase + wr*64 + i*16 + g16*4);
    #pragma unroll
    for (int j=0;j<4;j++){
      int col = bn + wc*64 + j*16 + c16;
      #pragma unroll
      for (int r=0;r<4;r++){
        int row = wr*64 + i*16 + g16*4 + r;
        float v = acc[i][j][r];
        if (MODE==2) v = v*(&di4.x)[r] + bias[col];
        out[(nbase + row)*HID + col] = v;
      }
    }
  }
}

// ---------------------------------------------------------------------------
// Weight prep: fp32 W[K,N] -> bf16 Wt[N,K], 64x64 LDS tile transpose.
// ---------------------------------------------------------------------------
struct PrepW { const float* w; int K; int N; };
struct PrepArgs { PrepW e[16]; };

__global__ __launch_bounds__(256) void prep_weights(PrepArgs pa, ushort* __restrict__ wtb)
{
  __shared__ ushort T[64][72];
  int wi = blockIdx.x;
  const float* W = pa.e[wi].w;
  int K = pa.e[wi].K, N = pa.e[wi].N;
  int tk_n = K>>6, tn_n = N>>6;
  int tile = blockIdx.y;
  if (tile >= tk_n*tn_n) return;
  int tk = tile % tk_n, tn = tile / tk_n;
  int t = threadIdx.x;
  int kr = t>>2, n0 = (t&3)*16;
  #pragma unroll
  for (int j=0;j<4;j++){
    float4 v = *(const float4*)(W + (size_t)(tk*64+kr)*N + tn*64 + n0 + j*4);
    T[n0+j*4+0][kr] = f2bf(v.x);
    T[n0+j*4+1][kr] = f2bf(v.y);
    T[n0+j*4+2][kr] = f2bf(v.z);
    T[n0+j*4+3][kr] = f2bf(v.w);
  }
  __syncthreads();
  ushort* out = wtb + (size_t)wi*65536;
  int nr = t>>2, k0 = (t&3)*16;
  *(short8*)(out + (size_t)(tn*64+nr)*K + tk*64 + k0)     = *(short8*)&T[nr][k0];
  *(short8*)(out + (size_t)(tn*64+nr)*K + tk*64 + k0 + 8) = *(short8*)&T[nr][k0+8];
}

// ---------------------------------------------------------------------------
// BatchNorm stats finalize (partials from mm_bf16 epilogue; 512 row-blocks)
// ---------------------------------------------------------------------------
__global__ __launch_bounds__(256) void bn_final(const float* __restrict__ part,
    const float* __restrict__ gamma, const float* __restrict__ beta, float* __restrict__ stats)
{
  int c = threadIdx.x;                           // grid 1, block 256
  float s=0.f, s2=0.f;
  for (int b=0;b<512;b++){ s += part[b*256+c]; s2 += part[131072 + b*256+c]; }
  const float invn = 1.0f/(float)NTOT;
  float mean = s*invn;
  float var  = s2*invn - mean*mean;
  float scl  = gamma[c]*rsqrtf(var + 1e-5f);
  stats[c]     = scl;
  stats[256+c] = beta[c] - mean*scl;
}

// ---------------------------------------------------------------------------
// bf16 MFMA matmul, BM=64 tile (doubles grid -> 4 blocks/CU):
// out[M,N] = A'[M,K] @ Wt[N,K](bf16) + bias.
// ATR=1: A' = relu(A*scale+shift).   EPI==1: out = skip + relu(out).
// BNF=1: per-column batch-stat partials -> part[(bm>>6)*256+col] (s2 +131072).
// TW=1 : write permuted interleaved bf16 hi/lo planes: each lane stores one
//        full 64B line per column (16 hi + 16 lo contiguous). rscale[row]
//        (actual row index) folded before the split.
// ---------------------------------------------------------------------------
template<int EPI, int ATR, int BNF, int TW>
__global__ __launch_bounds__(256) void mm_bf16(
    const float* __restrict__ A, const ushort* __restrict__ Wt,
    const float* __restrict__ bias, const float* __restrict__ skip,
    const float* __restrict__ bnst,
    float* __restrict__ out, ushort* __restrict__ twp,
    const float* __restrict__ rscale, float* __restrict__ part,
    int M, int K, int N)
{
  __shared__ ushort Al[64][72];
  __shared__ ushort Bl[128][72];
  const int t = threadIdx.x;
  const int bm = blockIdx.x*64, bn = blockIdx.y*128;
  const int w = t>>6, l = t&63;
  const int c16 = l&15, g16 = l>>4;
  const int ar = t>>2, ac = (t&3)*16;
  const int br = t>>1, bc = (t&1)*32;
  f32x4 acc[4][2];
  #pragma unroll
  for (int i=0;i<4;i++)
    #pragma unroll
    for (int j=0;j<2;j++) acc[i][j] = (f32x4){0.f,0.f,0.f,0.f};

  for (int k0=0; k0<K; k0+=64){
    const float* ap = A + (size_t)(bm+ar)*K + k0 + ac;
    #pragma unroll
    for (int j=0;j<2;j++){
      float4 v0 = *(const float4*)(ap + j*8);
      float4 v1 = *(const float4*)(ap + j*8 + 4);
      if (ATR){
        int cb = k0 + ac + j*8;
        float4 s0 = *(const float4*)(bnst + cb);
        float4 s1 = *(const float4*)(bnst + cb + 4);
        float4 h0 = *(const float4*)(bnst + 256 + cb);
        float4 h1 = *(const float4*)(bnst + 256 + cb + 4);
        v0.x=fmaxf(v0.x*s0.x+h0.x,0.f); v0.y=fmaxf(v0.y*s0.y+h0.y,0.f);
        v0.z=fmaxf(v0.z*s0.z+h0.z,0.f); v0.w=fmaxf(v0.w*s0.w+h0.w,0.f);
        v1.x=fmaxf(v1.x*s1.x+h1.x,0.f); v1.y=fmaxf(v1.y*s1.y+h1.y,0.f);
        v1.z=fmaxf(v1.z*s1.z+h1.z,0.f); v1.w=fmaxf(v1.w*s1.w+h1.w,0.f);
      }
      short8 p;
      p[0]=(short)f2bf(v0.x); p[1]=(short)f2bf(v0.y); p[2]=(short)f2bf(v0.z); p[3]=(short)f2bf(v0.w);
      p[4]=(short)f2bf(v1.x); p[5]=(short)f2bf(v1.y); p[6]=(short)f2bf(v1.z); p[7]=(short)f2bf(v1.w);
      *(short8*)&Al[ar][ac+j*8] = p;
    }
    const ushort* bp = Wt + (size_t)(bn+br)*K + k0 + bc;
    #pragma unroll
    for (int j=0;j<4;j++)
      *(short8*)&Bl[br][bc+j*8] = *(const short8*)(bp + j*8);
    __syncthreads();
    #pragma unroll
    for (int kk=0; kk<64; kk+=32){
      short8 af[4], bf[2];
      #pragma unroll
      for (int i=0;i<4;i++) af[i] = *(short8*)&Al[i*16+c16][kk+g16*8];
      #pragma unroll
      for (int j=0;j<2;j++) bf[j] = *(short8*)&Bl[w*32+j*16+c16][kk+g16*8];
      #pragma unroll
      for (int i=0;i<4;i++)
        #pragma unroll
        for (int j=0;j<2;j++)
          acc[i][j] = __builtin_amdgcn_mfma_f32_16x16x32_bf16(af[i], bf[j], acc[i][j], 0,0,0);
    }
    __syncthreads();
  }

  float sj[2]  = {0.f,0.f};
  float s2j[2] = {0.f,0.f};
  #pragma unroll
  for (int j=0;j<2;j++){
    const int col = bn + w*32 + j*16 + c16;
    const float bv = bias ? bias[col] : 0.f;
    if (TW){
      short8 h8a, h8b, l8a, l8b;
      #pragma unroll
      for (int i=0;i<4;i++){
        float4 rs = make_float4(1.f,1.f,1.f,1.f);
        if (rscale) rs = *(const float4*)(rscale + bm + i*16 + g16*4);
        #pragma unroll
        for (int r=0;r<4;r++){
          float v = acc[i][j][r] + bv;
          if (BNF){ sj[j]+=v; s2j[j]+=v*v; }
          float sv = v * (&rs.x)[r];
          ushort hb = f2bf(sv);
          ushort lb = f2bf(sv - bf2f(hb));
          if (i<2){ h8a[i*4+r]=(short)hb; l8a[i*4+r]=(short)lb; }
          else    { h8b[(i-2)*4+r]=(short)hb; l8b[(i-2)*4+r]=(short)lb; }
        }
      }
      ushort* dst = twp + (size_t)col*(size_t)(2*NTOT) + 2*bm + g16*32;
      *(short8*)(dst)      = h8a;
      *(short8*)(dst + 8)  = h8b;
      *(short8*)(dst + 16) = l8a;
      *(short8*)(dst + 24) = l8b;
    } else {
      #pragma unroll
      for (int i=0;i<4;i++){
        #pragma unroll
        for (int r=0;r<4;r++){
          int row = bm + i*16 + g16*4 + r;
          float v = acc[i][j][r] + bv;
          if (BNF){ sj[j]+=v; s2j[j]+=v*v; }
          if (EPI==1) v = skip[(size_t)row*N+col] + fmaxf(v,0.f);
          out[(size_t)row*N+col] = v;
        }
      }
    }
  }
  if (BNF){
    #pragma unroll
    for (int j=0;j<2;j++){
      float s = sj[j], s2 = s2j[j];
      s  += __shfl_xor(s, 16);  s  += __shfl_xor(s, 32);
      s2 += __shfl_xor(s2,16);  s2 += __shfl_xor(s2,32);
      if (g16==0){
        int col = bn + w*32 + j*16 + c16;
        part[(bm>>6)*256 + col]          = s;
        part[131072 + (bm>>6)*256 + col] = s2;
      }
    }
  }
}

// ---------------------------------------------------------------------------
// fp32 tiled matmul (tiny M: qp1 M=75, qp3 M=1)
// ---------------------------------------------------------------------------
template<int EPI>
__global__ __launch_bounds__(256) void mm_kernel(
    const float* __restrict__ A, const float* __restrict__ W,
    const float* __restrict__ bias, const float* __restrict__ skip,
    float* __restrict__ out, int M, int K, int N)
{
  __shared__ float As[16][68];   // [k][m]
  __shared__ float Ws[16][68];   // [k][n]
  const int t  = threadIdx.x;
  const int bm = blockIdx.x*64, bn = blockIdx.y*64;
  const int tx = t & 15, ty = t >> 4;
  const int lrow = t >> 2;
  const int lkc  = (t & 3) * 4;
  const int wkr  = t >> 4;
  const int wnc  = (t & 15) * 4;
  float acc[4][4] = {{0.f}};
  for (int k0 = 0; k0 < K; k0 += 16) {
    float4 av = make_float4(0.f,0.f,0.f,0.f);
    if (bm + lrow < M) av = *(const float4*)(A + (size_t)(bm+lrow)*K + k0 + lkc);
    float4 wv = *(const float4*)(W + (size_t)(k0+wkr)*N + bn + wnc);
    As[lkc+0][lrow]=av.x; As[lkc+1][lrow]=av.y; As[lkc+2][lrow]=av.z; As[lkc+3][lrow]=av.w;
    *(float4*)&Ws[wkr][wnc] = wv;
    __syncthreads();
    #pragma unroll
    for (int kk=0; kk<16; kk++){
      float4 a4 = *(float4*)&As[kk][ty*4];
      float4 b4 = *(float4*)&Ws[kk][tx*4];
      acc[0][0]+=a4.x*b4.x; acc[0][1]+=a4.x*b4.y; acc[0][2]+=a4.x*b4.z; acc[0][3]+=a4.x*b4.w;
      acc[1][0]+=a4.y*b4.x; acc[1][1]+=a4.y*b4.y; acc[1][2]+=a4.y*b4.z; acc[1][3]+=a4.y*b4.w;
      acc[2][0]+=a4.z*b4.x; acc[2][1]+=a4.z*b4.y; acc[2][2]+=a4.z*b4.z; acc[2][3]+=a4.z*b4.w;
      acc[3][0]+=a4.w*b4.x; acc[3][1]+=a4.w*b4.y; acc[3][2]+=a4.w*b4.z; acc[3][3]+=a4.w*b4.w;
    }
    __syncthreads();
  }
  #pragma unroll
  for (int i=0;i<4;i++){
    int r = bm + ty*4 + i;
    if (r >= M) continue;
    #pragma unroll
    for (int j=0;j<4;j++){
      int c = bn + tx*4 + j;
      float v = acc[i][j] + (bias ? bias[c] : 0.f);
      if (EPI==1) v = skip[(size_t)r*N + c] + fmaxf(v, 0.f);
      out[(size_t)r*N + c] = v;
    }
  }
}

// ---------------------------------------------------------------------------
// MFMA attention (validated). Block=(graph,head), 4 waves.
// ---------------------------------------------------------------------------
__global__ __launch_bounds__(256) void attn_mfma(
    const float* __restrict__ Qp, const float* __restrict__ Kd, const float* __restrict__ Vd,
    float* __restrict__ O, int qlen, int klen, int qgstride)
{
  __shared__ ushort Kbf[128*72];
  __shared__ ushort Vt[64*136];
  __shared__ ushort Pws[4][16*136];
  int g = blockIdx.x, h = blockIdx.y;
  int hd0 = h*DH;
  int t = threadIdx.x, w = t>>6, l = t&63;

  for (int idx=t; idx<128*16; idx+=256){
    int k = idx>>4, d4 = (idx&15)*4;
    float4 kv = make_float4(0.f,0.f,0.f,0.f), vv = kv;
    if (k < klen){
      kv = *(const float4*)(Kd + ((size_t)g*klen + k)*HID + hd0 + d4);
      vv = *(const float4*)(Vd + ((size_t)g*klen + k)*HID + hd0 + d4);
    }
    ushort4 kb = make_ushort4(f2bf(kv.x), f2bf(kv.y), f2bf(kv.z), f2bf(kv.w));
    *(ushort4*)&Kbf[k*72 + d4] = kb;
    Vt[(d4+0)*136 + k] = f2bf(vv.x);
    Vt[(d4+1)*136 + k] = f2bf(vv.y);
    Vt[(d4+2)*136 + k] = f2bf(vv.z);
    Vt[(d4+3)*136 + k] = f2bf(vv.w);
  }
  __syncthreads();

  const int c16 = l & 15, g16 = l >> 4;
  const float scl = 1.0f/16.0f;
  int qtiles = (qlen + 15) >> 4;
  for (int qt = w; qt < qtiles; qt += 4){
    int qbase = qt*16;
    int qrow = qbase + c16; if (qrow > qlen-1) qrow = qlen-1;
    const float* qr = Qp + (size_t)g*qgstride + (size_t)qrow*HID + hd0 + g16*8;
    short8 qa[2];
    #pragma unroll
    for (int dh=0; dh<2; dh++){
      float4 x0 = *(const float4*)(qr + dh*32);
      float4 x1 = *(const float4*)(qr + dh*32 + 4);
      short8 f;
      f[0]=(short)f2bf(x0.x); f[1]=(short)f2bf(x0.y); f[2]=(short)f2bf(x0.z); f[3]=(short)f2bf(x0.w);
      f[4]=(short)f2bf(x1.x); f[5]=(short)f2bf(x1.y); f[6]=(short)f2bf(x1.z); f[7]=(short)f2bf(x1.w);
      qa[dh]=f;
    }
    float p[8][4];
    #pragma unroll
    for (int kt=0; kt<8; kt++){
      f32x4 a = {0.f,0.f,0.f,0.f};
      short8 b0 = *(short8*)&Kbf[(kt*16+c16)*72 + g16*8];
      short8 b1 = *(short8*)&Kbf[(kt*16+c16)*72 + 32 + g16*8];
      a = __builtin_amdgcn_mfma_f32_16x16x32_bf16(qa[0], b0, a, 0,0,0);
      a = __builtin_amdgcn_mfma_f32_16x16x32_bf16(qa[1], b1, a, 0,0,0);
      int k = kt*16 + c16;
      #pragma unroll
      for (int r=0; r<4; r++) p[kt][r] = (k < klen) ? a[r]*scl : -1e30f;
    }
    float m[4], sum[4];
    #pragma unroll
    for (int r=0; r<4; r++){
      float mm = p[0][r];
      #pragma unroll
      for (int kt=1; kt<8; kt++) mm = fmaxf(mm, p[kt][r]);
      for (int o=1; o<16; o<<=1) mm = fmaxf(mm, __shfl_xor(mm, o));
      m[r] = mm;
    }
    #pragma unroll
    for (int r=0; r<4; r++){
      float s = 0.f;
      #pragma unroll
      for (int kt=0; kt<8; kt++){ p[kt][r] = __expf(p[kt][r]-m[r]); s += p[kt][r]; }
      for (int o=1; o<16; o<<=1) s += __shfl_xor(s, o);
      sum[r] = 1.0f/s;
    }
    #pragma unroll
    for (int kt=0; kt<8; kt++)
      #pragma unroll
      for (int r=0; r<4; r++)
        Pws[w][(g16*4+r)*136 + kt*16 + c16] = f2bf(p[kt][r]*sum[r]);
    #pragma unroll
    for (int dt=0; dt<4; dt++){
      f32x4 o4 = {0.f,0.f,0.f,0.f};
      #pragma unroll
      for (int ks=0; ks<4; ks++){
        short8 pa = *(short8*)&Pws[w][c16*136 + ks*32 + g16*8];
        short8 vb = *(short8*)&Vt[(dt*16+c16)*136 + ks*32 + g16*8];
        o4 = __builtin_amdgcn_mfma_f32_16x16x32_bf16(pa, vb, o4, 0,0,0);
      }
      #pragma unroll
      for (int r=0; r<4; r++){
        int q2 = qbase + g16*4 + r;
        if (q2 < qlen){
          int col = hd0 + dt*16 + c16;
          O[((size_t)g*qlen + q2)*HID + col] =
              Qp[(size_t)g*qgstride + (size_t)q2*HID + col] + o4[r];
        }
      }
    }
  }
}

// ---------------------------------------------------------------------------
extern "C" void kernel_launch(void* const* d_in, const int* in_sizes, int n_in,
                              void* d_out, int out_size, void* d_ws, size_t ws_size,
                              hipStream_t stream)
{
  (void)in_sizes; (void)n_in; (void)out_size; (void)ws_size;
  const float* x      = (const float*)d_in[0];
  const int*   ei     = (const int*)d_in[1];
  const float* g0_W1=(const float*)d_in[3],  *g0_b1=(const float*)d_in[4],  *g0_ga1=(const float*)d_in[5],  *g0_be1=(const float*)d_in[6];
  const float* g0_W2=(const float*)d_in[7],  *g0_b2=(const float*)d_in[8],  *g0_ga2=(const float*)d_in[9],  *g0_be2=(const float*)d_in[10];
  const float* g1_W1=(const float*)d_in[11], *g1_b1=(const float*)d_in[12], *g1_ga1=(const float*)d_in[13], *g1_be1=(const float*)d_in[14];
  const float* g1_W2=(const float*)d_in[15], *g1_b2=(const float*)d_in[16], *g1_ga2=(const float*)d_in[17], *g1_be2=(const float*)d_in[18];
  const float* lin1_W=(const float*)d_in[19], *lin1_b=(const float*)d_in[20];
  const float* S1=(const float*)d_in[21];
  const float* p1_Wq=(const float*)d_in[22], *p1_Wk=(const float*)d_in[23], *p1_Wv=(const float*)d_in[24], *p1_Wo=(const float*)d_in[25];
  const float* p1_bq=(const float*)d_in[26], *p1_bk=(const float*)d_in[27], *p1_bv=(const float*)d_in[28], *p1_bo=(const float*)d_in[29];
  const float* s2_Wq=(const float*)d_in[30], *s2_Wk=(const float*)d_in[31], *s2_Wv=(const float*)d_in[32], *s2_Wo=(const float*)d_in[33];
  const float* s2_bq=(const float*)d_in[34], *s2_bk=(const float*)d_in[35], *s2_bv=(const float*)d_in[36], *s2_bo=(const float*)d_in[37];
  const float* p3_Wq=(const float*)d_in[38], *p3_Wk=(const float*)d_in[39], *p3_Wv=(const float*)d_in[40], *p3_Wo=(const float*)d_in[41];
  const float* p3_bq=(const float*)d_in[42], *p3_bk=(const float*)d_in[43], *p3_bv=(const float*)d_in[44], *p3_bo=(const float*)d_in[45];
  const float* S3=(const float*)d_in[46];
  const float* lin2_W=(const float*)d_in[47], *lin2_b=(const float*)d_in[48];

  const int* src = ei;
  const int* dst = ei + EDGES;

  // workspace layout (~147 MB)
  float* F = (float*)d_ws;
  const size_t SZ = (size_t)NTOT*HID;              // 8388608 floats
  float* R0=F, *R1=F+SZ, *R2=F+2*SZ, *R3=F+3*SZ;   // R1,R2 adjacent (KV planes)
  float* part  = F + 4*SZ;           // 262144 (512 row-blocks x 256, s2 +131072)
  float* stats = part + 262144;      // 512
  float* dinv  = stats + 512;        // 32768
  float* qp1   = dinv + 32768;       // 19200
  float* qp3   = qp1 + 19200;        // 256
  float* o3    = qp3 + 256;          // 65536
  float* xf    = o3 + 65536;         // 65536
  ushort* adjg = (ushort*)(xf + 65536);            // GG*16384 bf16 = 8.39 MB
  ushort* wtb  = adjg + (size_t)GG*NN*NN;          // 16*65536 bf16

  const dim3 B256(256);
  const dim3 mmBig(512,2), mmMid(300,2);
  #define WT(i) (wtb + (size_t)(i)*65536)

  // --- weight prep (16 weights -> bf16 transposed) ---
  PrepArgs pa;
  pa.e[0]  = {g0_W1, 128, 256};
  pa.e[1]  = {g0_W2, 256, 256};
  pa.e[2]  = {g1_W1, 256, 256};
  pa.e[3]  = {g1_W2, 256, 256};
  pa.e[4]  = {lin1_W,256, 256};
  pa.e[5]  = {p1_Wk, 256, 256};
  pa.e[6]  = {p1_Wv, 256, 256};
  pa.e[7]  = {p1_Wo, 256, 256};
  pa.e[8]  = {s2_Wk, 256, 256};
  pa.e[9]  = {s2_Wv, 256, 256};
  pa.e[10] = {s2_Wq, 256, 256};
  pa.e[11] = {s2_Wo, 256, 256};
  pa.e[12] = {p3_Wk, 256, 256};
  pa.e[13] = {p3_Wv, 256, 256};
  pa.e[14] = {p3_Wo, 256, 256};
  pa.e[15] = {lin2_W,256, 128};
  prep_weights<<<dim3(16,16),B256,0,stream>>>(pa, wtb);

  // --- graph structure: dense per-graph adjacency (columns permuted) ---
  adj_build<<<GG,B256,0,stream>>>(src,dst,adjg,dinv);

  // --- GIN layer 0 ---
  agg_mfma<128,0><<<dim3(GG,1),B256,0,stream>>>(adjg, x, R0);
  mm_bf16<0,0,1,0><<<mmBig,B256,0,stream>>>(R0, WT(0), g0_b1, nullptr, nullptr, R1, nullptr, nullptr, part, NTOT,128,HID);
  bn_final<<<1,B256,0,stream>>>(part, g0_ga1, g0_be1, stats);
  // h2 = relu(bn1(h1)) @ W2 + b2 : permuted bf16 hi/lo planes + bn partials
  mm_bf16<0,1,1,1><<<mmBig,B256,0,stream>>>(R1, WT(1), g0_b2, nullptr, stats, nullptr, (ushort*)R2, nullptr, part, NTOT,256,HID);
  bn_final<<<1,B256,0,stream>>>(part, g0_ga2, g0_be2, stats);

  // --- GIN layer 1 (bn2+outer-relu of layer0 fused at plane load) ---
  agg_gemm<1><<<dim3(GG,2),B256,0,stream>>>(adjg, (ushort*)R2, nullptr, stats, nullptr, nullptr, R0, nullptr);
  mm_bf16<0,0,1,0><<<mmBig,B256,0,stream>>>(R0, WT(2), g1_b1, nullptr, nullptr, R1, nullptr, nullptr, part, NTOT,256,HID);
  bn_final<<<1,B256,0,stream>>>(part, g1_ga1, g1_be1, stats);
  mm_bf16<0,1,1,0><<<mmBig,B256,0,stream>>>(R1, WT(3), g1_b2, nullptr, stats, R2, nullptr, nullptr, part, NTOT,256,HID);
  bn_final<<<1,B256,0,stream>>>(part, g1_ga2, g1_be2, stats);

  // --- lin1 (bn2+outer-relu of layer1 fused into A-stage) ---
  mm_bf16<0,1,0,0><<<mmBig,B256,0,stream>>>(R2, WT(4), lin1_b, nullptr, stats, R0, nullptr, nullptr, nullptr, NTOT,256,HID); // xl -> R0

  // --- GMPool_G (p1): fused K,V plane producer (N=512, dinv folded) ---
  mm_bf16<0,0,0,1><<<dim3(512,4),B256,0,stream>>>(R0, WT(5), nullptr, nullptr, nullptr, nullptr, (ushort*)R1, dinv, nullptr, NTOT,256,512);
  agg_gemm<2><<<dim3(GG,4),B256,0,stream>>>(adjg, (ushort*)R1, (ushort*)R1 + (size_t)256*(size_t)(2*NTOT), dinv, p1_bk, p1_bv, R0, R3); // Kd->R0, Vd->R3
  mm_kernel<0><<<dim3(2,4),B256,0,stream>>>(S1, p1_Wq, p1_bq, nullptr, qp1, 75,256,HID);
  attn_mfma<<<dim3(GG,4),B256,0,stream>>>(qp1, R0, R3, R1, 75,128, 0);     // O1 -> R1
  mm_bf16<1,0,0,0><<<mmMid,B256,0,stream>>>(R1, WT(7), p1_bo, R1, nullptr, R2, nullptr, nullptr, nullptr, 19200,256,HID); // Xp -> R2

  // --- SelfAtt (s2) ---
  mm_bf16<0,0,0,0><<<mmMid,B256,0,stream>>>(R2, WT(8),  s2_bk, nullptr, nullptr, R0, nullptr, nullptr, nullptr, 19200,256,HID);
  mm_bf16<0,0,0,0><<<mmMid,B256,0,stream>>>(R2, WT(9),  s2_bv, nullptr, nullptr, R3, nullptr, nullptr, nullptr, 19200,256,HID);
  mm_bf16<0,0,0,0><<<mmMid,B256,0,stream>>>(R2, WT(10), s2_bq, nullptr, nullptr, R1, nullptr, nullptr, nullptr, 19200,256,HID);
  attn_mfma<<<dim3(GG,4),B256,0,stream>>>(R1, R0, R3, R2, 75,75, 75*HID);  // O2 -> R2
  mm_bf16<1,0,0,0><<<mmMid,B256,0,stream>>>(R2, WT(11), s2_bo, R2, nullptr, R0, nullptr, nullptr, nullptr, 19200,256,HID); // Xp2 -> R0

  // --- GMPool_I (p3) ---
  mm_bf16<0,0,0,0><<<mmMid,B256,0,stream>>>(R0, WT(12), p3_bk, nullptr, nullptr, R1, nullptr, nullptr, nullptr, 19200,256,HID);
  mm_bf16<0,0,0,0><<<mmMid,B256,0,stream>>>(R0, WT(13), p3_bv, nullptr, nullptr, R2, nullptr, nullptr, nullptr, 19200,256,HID);
  mm_kernel<0><<<dim3(1,4),B256,0,stream>>>(S3, p3_Wq, p3_bq, nullptr, qp3, 1,256,HID);
  attn_mfma<<<dim3(GG,4),B256,0,stream>>>(qp3, R1, R2, o3, 1,75, 0);       // O3 -> [G,256]
  mm_bf16<1,0,0,0><<<dim3(4,2),B256,0,stream>>>(o3, WT(14), p3_bo, o3, nullptr, xf, nullptr, nullptr, nullptr, 256,256,HID);

  // --- lin2 ---
  mm_bf16<0,0,0,0><<<dim3(4,1),B256,0,stream>>>(xf, WT(15), lin2_b, nullptr, nullptr, (float*)d_out, nullptr, nullptr, nullptr, 256,256,128);
}